// Round 1
// baseline (515.670 us; speedup 1.0000x reference)
//
#include <hip/hip_runtime.h>

#define NEG (-1e30f)

// B=2048, T=256, C=128, L=32, S=65 (specialized; asserts via launch config)
__global__ __launch_bounds__(256, 4) void ctc_loss_kernel(
    const int* __restrict__ y_true,   // [B, 32]
    const float* __restrict__ y_pred, // [B, 256, 128]
    float* __restrict__ out)          // [B]
{
    const int b    = blockIdx.x;
    const int tid  = threadIdx.x;
    const int lane = tid & 63;
    const int wave = tid >> 6;

    __shared__ int   lab[32];
    __shared__ float lpv[256 * 33];   // per t: [0]=lp(blank), [1+k]=lp(label k)

    if (tid < 32) lab[tid] = y_true[b * 32 + tid];
    __syncthreads();

    const float* __restrict__ Y = y_pred + (size_t)b * 256 * 128;

    // ---- Phase 1: log-softmax per t, gather blank + 32 labels into LDS ----
    // wave w handles t = w, w+4, ...  Each lane loads float2 (classes 2*lane, 2*lane+1).
    for (int t = wave; t < 256; t += 4) {
        float2 v = ((const float2*)(Y + t * 128))[lane];
        float mv = fmaxf(v.x, v.y);
        #pragma unroll
        for (int off = 32; off; off >>= 1) mv = fmaxf(mv, __shfl_xor(mv, off));
        float se = __expf(v.x - mv) + __expf(v.y - mv);
        #pragma unroll
        for (int off = 32; off; off >>= 1) se += __shfl_xor(se, off);
        float lse = mv + __logf(se);

        // lane 0 -> blank(class 0); lanes 1..32 -> labels; gather via in-wave shuffle
        int c = (lane >= 1 && lane <= 32) ? lab[lane - 1] : 0;
        float g0 = __shfl(v.x, c >> 1);
        float g1 = __shfl(v.y, c >> 1);
        float g  = (c & 1) ? g1 : g0;
        if (lane <= 32) lpv[t * 33 + lane] = g - lse;
    }
    __syncthreads();

    // ---- Phase 2: forward recursion, wave 0 only, shuffle-based ----
    if (wave == 0) {
        const int s = lane;                       // state index 0..63; state 64 replicated
        // can_skip[s]: s odd, s>=3, ext[s] != ext[s-2]  (labels all non-blank by input spec)
        const bool can_skip = (s & 1) && (s >= 3) && (lab[s >> 1] != lab[(s >> 1) - 1]);
        const int  lpidx    = (s & 1) ? (1 + (s >> 1)) : 0;

        float alpha = (s == 0) ? lpv[0] : ((s == 1) ? lpv[1] : NEG);
        float a64   = NEG;                        // alpha[64], replicated in every lane

        for (int t = 1; t < 256; ++t) {
            float a1 = __shfl_up(alpha, 1);
            if (s == 0) a1 = NEG;
            float a2 = __shfl_up(alpha, 2);
            if (!can_skip) a2 = NEG;
            float aold63 = __shfl(alpha, 63);     // old alpha[63] broadcast

            float lp0 = lpv[t * 33];              // lp(blank) at t
            float lp  = lpv[t * 33 + lpidx];

            // alpha[s] = logaddexp3(alpha, a1, a2) + lp
            float m = fmaxf(fmaxf(alpha, a1), a2);
            alpha = m + __logf(__expf(alpha - m) + __expf(a1 - m) + __expf(a2 - m)) + lp;

            // alpha[64] = logaddexp(a64, old alpha[63]) + lp(blank)  (even state: no skip)
            float m2 = fmaxf(a64, aold63);
            a64 = m2 + __logf(__expf(a64 - m2) + __expf(aold63 - m2)) + lp0;
        }

        if (s == 63) {
            float m = fmaxf(alpha, a64);
            out[b] = -(m + __logf(__expf(alpha - m) + __expf(a64 - m)));
        }
    }
}

extern "C" void kernel_launch(void* const* d_in, const int* in_sizes, int n_in,
                              void* d_out, int out_size, void* d_ws, size_t ws_size,
                              hipStream_t stream) {
    const int*   y_true = (const int*)d_in[0];
    const float* y_pred = (const float*)d_in[1];
    float*       out    = (float*)d_out;
    const int B = 2048;
    ctc_loss_kernel<<<B, 256, 0, stream>>>(y_true, y_pred, out);
}